// Round 3
// baseline (172.743 us; speedup 1.0000x reference)
//
#include <hip/hip_runtime.h>
#include <math.h>

#define NB    128
#define NG    52
#define NGG   2704          // NG*NG
#define NA    3
#define NCLS  15
#define NCH   20
#define NQ    8112          // NA*NGG
#define TOTAL 1038336       // NB*NQ
#define BLK   256
#define NTHREADS (TOTAL/2)  // 519168, one thread per 2 cells
#define NBLK  (NTHREADS/BLK) // 2028 (exact)
#define NPART (NBLK*4)      // per-wave partials

__device__ __forceinline__ float sigmoidf(float z) { return 1.0f / (1.0f + expf(-z)); }

// ---- main kernel: transform + direct aligned float4 stores, no LDS xpose ----
__global__ __launch_bounds__(BLK) void main_kernel(const float* __restrict__ x,
                                                   float* __restrict__ out,
                                                   float* __restrict__ partials) {
    int t = threadIdx.x;
    int T = blockIdx.x * BLK + t;      // thread handles cells 2T, 2T+1
    int cell0 = T * 2;
    int b  = cell0 / NQ;
    int r  = cell0 - b * NQ;
    int a  = r / NGG;
    int ji = r - a * NGG;              // even; both cells in same (b,a) plane

    const float2* __restrict__ xp =
        (const float2*)(x + ((size_t)(b*60 + a*20)) * NGG) + (ji >> 1);

    float za[NCH], zb[NCH];
    #pragma unroll
    for (int c = 0; c < NCH; c++) {
        float2 zz = xp[c * (NGG/2)];
        za[c] = zz.x; zb[c] = zz.y;
    }

    // window w[0..39] = out[4+40T .. 43+40T]:
    //   w[0..16]  = cell0 ch3..19
    //   w[17..36] = cell1 ch0..19
    //   w[37..39] = cell2 (=2T+2) ch0..2   (from lane+1 via shfl)
    float w[40];
    float tsum;

    // cell0 (2T): ch0..2 computed for the *previous* window (shfl'd out)
    float va0 = 8.0f * sigmoidf(za[0]);
    float va1 = 8.0f * sigmoidf(za[1]);
    float va2 = 8.0f * za[2];
    w[0] = 8.0f * za[3];
    {
        float conf = sigmoidf(za[4]);
        w[1] = conf;
        tsum = -fmaxf(logf(1.0f - conf), -100.0f);
        float m = za[5];
        #pragma unroll
        for (int c = 6; c < NCH; c++) m = fmaxf(m, za[c]);
        float s = 0.0f;
        #pragma unroll
        for (int c = 0; c < NCLS; c++) { w[2+c] = expf(za[5+c] - m); s += w[2+c]; }
        float inv = 1.0f / s;
        #pragma unroll
        for (int c = 0; c < NCLS; c++) w[2+c] *= inv;
    }

    // cell1 (2T+1): full 20 channels
    w[17] = 8.0f * sigmoidf(zb[0]);
    w[18] = 8.0f * sigmoidf(zb[1]);
    w[19] = 8.0f * zb[2];
    w[20] = 8.0f * zb[3];
    {
        float conf = sigmoidf(zb[4]);
        w[21] = conf;
        tsum += -fmaxf(logf(1.0f - conf), -100.0f);
        float m = zb[5];
        #pragma unroll
        for (int c = 6; c < NCH; c++) m = fmaxf(m, zb[c]);
        float s = 0.0f;
        #pragma unroll
        for (int c = 0; c < NCLS; c++) { w[22+c] = expf(zb[5+c] - m); s += w[22+c]; }
        float inv = 1.0f / s;
        #pragma unroll
        for (int c = 0; c < NCLS; c++) w[22+c] *= inv;
    }

    // neighbor cell (2T+2) ch0..2: lane+1's va0..va2
    w[37] = __shfl_down(va0, 1, 64);
    w[38] = __shfl_down(va1, 1, 64);
    w[39] = __shfl_down(va2, 1, 64);
    if ((t & 63) == 63) {
        int cell2 = cell0 + 2;
        if (cell2 < TOTAL) {
            int b2  = cell2 / NQ;
            int r2  = cell2 - b2 * NQ;
            int a2  = r2 / NGG;
            int ji2 = r2 - a2 * NGG;
            const float* q = x + ((size_t)(b2*60 + a2*20)) * NGG + ji2;
            float z0 = q[0], z1 = q[(size_t)NGG], z2 = q[(size_t)2*NGG];
            w[37] = 8.0f * sigmoidf(z0);
            w[38] = 8.0f * sigmoidf(z1);
            w[39] = 8.0f * z2;
        }
    }

    // aligned float4 stores of the window
    size_t W = 4 + (size_t)T * 40;       // out float index, W % 4 == 0
    float4* __restrict__ op = (float4*)(out + W);
    if (T != NTHREADS - 1) {
        #pragma unroll
        for (int k = 0; k < 10; k++)
            op[k] = make_float4(w[4*k], w[4*k+1], w[4*k+2], w[4*k+3]);
    } else {
        #pragma unroll
        for (int k = 0; k < 9; k++)
            op[k] = make_float4(w[4*k], w[4*k+1], w[4*k+2], w[4*k+3]);
        out[W + 36] = w[36];             // last valid out float
    }
    if (T == 0) { out[1] = va0; out[2] = va1; out[3] = va2; }

    // per-wave noobj partial (no barrier, no atomic)
    #pragma unroll
    for (int off = 32; off > 0; off >>= 1) tsum += __shfl_down(tsum, off, 64);
    if ((t & 63) == 0) partials[blockIdx.x * 4 + (t >> 6)] = tsum;
}

// ---------------- finish: partial sum + per-batch corrections + loss ------
__global__ void finish_kernel(const float* __restrict__ labels,
                              const float* __restrict__ partials,
                              float* __restrict__ out) {
    int t = threadIdx.x;   // 256 threads
    float s = 0.0f;
    for (int q = t; q < NPART; q += 256) s += partials[q];

    float corr_part = 0.0f;
    if (t < NB) {
        int b = t;
        float gx = labels[b*5+0] * (float)NG;
        float gy = labels[b*5+1] * (float)NG;
        float gw = labels[b*5+2] * (float)NG;
        float gh = labels[b*5+3] * (float)NG;
        int gcls = (int)labels[b*5+4];
        int gi = (int)gx, gj = (int)gy;
        const float aw[3] = {12.0f, 9.875f, 10.125f};
        const float ah[3] = {28.75f, 23.25f, 16.625f};
        float iou[3];
        #pragma unroll
        for (int a = 0; a < 3; a++) {
            float inter = fminf(aw[a], gw) * fminf(ah[a], gh);
            iou[a] = inter / (aw[a]*ah[a] + 1e-16f + gw*gh - inter);
        }
        int best = 0; float bv = iou[0];
        if (iou[1] > bv) { best = 1; bv = iou[1]; }
        if (iou[2] > bv) { best = 2; bv = iou[2]; }
        float txv = gx - (float)gi;
        float tyv = gy - (float)gj;
        float twv = logf(gw / aw[best] + 1e-16f);
        float thv = logf(gh / ah[best] + 1e-16f);

        float corr = 0.0f;
        #pragma unroll
        for (int a = 0; a < 3; a++) {
            int q = a*NGG + gj*NG + gi;
            const float* ob = out + 1 + ((size_t)b*NQ + q) * NCH;
            float conf = ob[4];
            bool isbest = (a == best);
            if (isbest || iou[a] > 0.5f) {
                corr += -fmaxf(logf(1.0f - conf), -100.0f);   // noobj==0 here: remove
            }
            if (isbest) {
                corr_part += -fmaxf(logf(conf), -100.0f);     // obj conf BCE (t=1)
                float px = ob[0]*0.125f, py = ob[1]*0.125f;
                float pw = ob[2]*0.125f, ph = ob[3]*0.125f;
                corr_part += fabsf(px - txv) + fabsf(py - tyv)
                           + fabsf(pw - twv) + fabsf(ph - thv);
                for (int c = 0; c < NCLS; c++) {
                    float p = ob[5 + c];
                    if (c == gcls) corr_part += -fmaxf(logf(p),        -100.0f);
                    else           corr_part += -fmaxf(logf(1.0f - p), -100.0f);
                }
            }
        }
        corr_part -= 100.0f * corr;
    }

    __shared__ float red[256];
    red[t] = 100.0f * s + corr_part;
    __syncthreads();
    for (int s2 = 128; s2 > 0; s2 >>= 1) {
        if (t < s2) red[t] += red[t + s2];
        __syncthreads();
    }
    if (t == 0) out[0] = red[0];
}

extern "C" void kernel_launch(void* const* d_in, const int* in_sizes, int n_in,
                              void* d_out, int out_size, void* d_ws, size_t ws_size,
                              hipStream_t stream) {
    const float* x      = (const float*)d_in[0];
    const float* labels = (const float*)d_in[1];
    float* out = (float*)d_out;
    float* ws  = (float*)d_ws;

    hipLaunchKernelGGL(main_kernel,   dim3(NBLK), dim3(BLK), 0, stream, x, out, ws);
    hipLaunchKernelGGL(finish_kernel, dim3(1),    dim3(256), 0, stream, labels, ws, out);
}